// Round 13
// baseline (160.413 us; speedup 1.0000x reference)
//
#include <hip/hip_runtime.h>

// IAF chain encoder, fully fused. Round 13: TWO desynchronized blocks per CU.
// r8-r12 (5 schedules) all ~73us with every pipe <45% -> pipes not
// overlapping: 1 block/CU, 16 barrier-locked waves in lockstep. Fix: 16-row
// blocks (512 thr, 8 waves, 49.4KB LDS) -> 2 resident blocks/CU whose phases
// drift -> one block's barrier/epilogue bubbles filled by the other's gemm.
// Per-wave: 4 tiles as two mirror pairs (2w,31-2w),(2w+1,30-2w) -- exact
// balance (5/9/9 cp) -- r12's proven hybrid loop, M=16.

typedef _Float16 f16;
typedef __attribute__((ext_vector_type(8))) _Float16 f16x8;
typedef __attribute__((ext_vector_type(4))) float f32x4;

#define NB 8192
#define ND 256
#define NH 512
#define NT 4
#define ROWS 16
#define XSTR 260   // xbuf row stride (floats)

// ws layout (fp16 els), fragment-native [T][tile=32][ks<KSMAX][lane=64][8]
// (fixed tile stride = KSMAX*512 els; chunks >= true nks(tile) are ZEROS)
#define W1F_OFF 0                        // KSMAX=8  : T*32*8*512  = T*NH*ND
#define W2F_OFF (NT*NH*ND)               // KSMAX=16 : T*32*16*512 = T*NH*NH
#define W3F_OFF (W2F_OFF + NT*NH*NH)     // KSMAX=16
#define WS_ELEMS (W3F_OFF + NT*NH*NH)    // 2,621,440 els = 5.24 MB

// Degree-sorted hidden permutation. deg_h[n] = 1 + n%255 over n in [0,512).
__device__ __forceinline__ int h_orig(int j) {
  if (j < 3) return j == 0 ? 0 : (j == 1 ? 255 : 510);
  if (j < 6) return j == 3 ? 1 : (j == 4 ? 256 : 511);
  int d = j >> 1;
  return (j & 1) ? (d + 254) : (d - 1);
}
__device__ __forceinline__ int h_deg(int j) {
  return (j < 3) ? 1 : (j < 6) ? 2 : (j >> 1);
}

// M1[k][j]: k <= deg(j)-1 ; M2[k][j]: deg(k) <= deg(j) ; M3[k][n]: deg(k) <= n>>1
__global__ void prep_weights(const float* __restrict__ W1,
                             const float* __restrict__ W2,
                             const float* __restrict__ W3,
                             f16* __restrict__ ws)
{
  int idx = blockIdx.x * blockDim.x + threadIdx.x;
  if (idx >= WS_ELEMS) return;
  float v;
  if (idx < W2F_OFF) {
    int t = idx >> 17, r = idx & ((1 << 17) - 1);     // 32*8*512 = 131072
    int e = r & 7, lane = (r >> 3) & 63, ks = (r >> 9) & 7, tile = r >> 12;
    int j = tile * 16 + (lane & 15);                  // sorted hidden col
    int k = ks * 32 + (lane >> 4) * 8 + e;            // raw input row
    v = (k <= h_deg(j) - 1) ? W1[t * (ND * NH) + k * NH + h_orig(j)] : 0.f;
  } else if (idx < W3F_OFF) {
    int q = idx - W2F_OFF;
    int t = q >> 18, r = q & ((1 << 18) - 1);         // 32*16*512 = 262144
    int e = r & 7, lane = (r >> 3) & 63, ks = (r >> 9) & 15, tile = r >> 13;
    int j = tile * 16 + (lane & 15);                  // sorted hidden col
    int k = ks * 32 + (lane >> 4) * 8 + e;            // sorted hidden row
    v = (h_deg(k) <= h_deg(j)) ? W2[t * (NH * NH) + h_orig(k) * NH + h_orig(j)] : 0.f;
  } else {
    int q = idx - W3F_OFF;
    int t = q >> 18, r = q & ((1 << 18) - 1);
    int e = r & 7, lane = (r >> 3) & 63, ks = (r >> 9) & 15, tile = r >> 13;
    int n = tile * 16 + (lane & 15);                  // raw output col
    int k = ks * 32 + (lane >> 4) * 8 + e;            // sorted hidden row
    v = (h_deg(k) <= (n >> 1)) ? W3[t * (NH * 2 * ND) + h_orig(k) * (2 * ND) + n] : 0.f;
  }
  ws[idx] = (f16)v;
}

#define MFMA16 __builtin_amdgcn_mfma_f32_16x16x32_f16

// Mirror-paired hybrid gemm, M=16 (one row-tile). Tiles S (near, ncS) and
// B (far, ncB>=ncS). Shared prefix feeds both from one A-read; solo tail B.
// Named regs, dist-1 double buffer (the proven scratch-free shape).
template<int SSTRB>
__device__ __forceinline__ void gemm_hyb16(const f16* srcA,
                                           const f16* __restrict__ wtS,
                                           const f16* __restrict__ wtB,
                                           int ncS, int ncB,
                                           int lrow, int lk8,
                                           f32x4 &aS, f32x4 &aB)
{
  const f32x4 z = {0.f, 0.f, 0.f, 0.f};
  aS = z; aB = z;
  const int swz0 = (lrow & 7) << 4;

  f16x8 cS0 = *(const f16x8*)(wtS);
  f16x8 cS1 = *(const f16x8*)(wtS + 512);
  f16x8 cB0 = *(const f16x8*)(wtB);
  f16x8 cB1 = *(const f16x8*)(wtB + 512);
  for (int c = 0; ; ++c) {
    f16x8 nS0, nS1, nB0, nB1;
    const bool more = (c + 1 < ncS);               // wave-uniform
    if (more) {
      const f16* pS = wtS + (c + 1) * 1024;
      const f16* pB = wtB + (c + 1) * 1024;
      nS0 = *(const f16x8*)(pS);
      nS1 = *(const f16x8*)(pS + 512);
      nB0 = *(const f16x8*)(pB);
      nB1 = *(const f16x8*)(pB + 512);
    }
    #pragma unroll
    for (int u = 0; u < 2; ++u) {
      int kb = 128 * c + u * 64 + lk8 * 16;
      f16x8 a0 = *(const f16x8*)((const char*)srcA + ((lrow * SSTRB + kb) ^ swz0));
      aS = MFMA16(a0, u ? cS1 : cS0, aS, 0, 0, 0);
      aB = MFMA16(a0, u ? cB1 : cB0, aB, 0, 0, 0);
    }
    if (!more) break;
    cS0 = nS0; cS1 = nS1; cB0 = nB0; cB1 = nB1;
  }

  if (ncS < ncB) {
    f16x8 dB0 = *(const f16x8*)(wtB + ncS * 1024);
    f16x8 dB1 = *(const f16x8*)(wtB + ncS * 1024 + 512);
    for (int c = ncS; ; ++c) {
      f16x8 nB0, nB1;
      const bool more = (c + 1 < ncB);             // wave-uniform
      if (more) {
        const f16* pB = wtB + (c + 1) * 1024;
        nB0 = *(const f16x8*)(pB);
        nB1 = *(const f16x8*)(pB + 512);
      }
      #pragma unroll
      for (int u = 0; u < 2; ++u) {
        int kb = 128 * c + u * 64 + lk8 * 16;
        f16x8 a0 = *(const f16x8*)((const char*)srcA + ((lrow * SSTRB + kb) ^ swz0));
        aB = MFMA16(a0, u ? dB1 : dB0, aB, 0, 0, 0);
      }
      if (!more) break;
      dB0 = nB0; dB1 = nB1;
    }
  }
}

// relu(acc + bias) -> fp16 LDS tile [16][512] (sorted cols), swizzled,
// row stride 1024B. Even lanes store the (n,n+1) b32 pair for their row.
__device__ __forceinline__ void epi16(f32x4 a, const float* __restrict__ bias_t,
                                      f16* dst, int np, int lrow, int lk8)
{
  const bool ev = (lrow & 1) == 0;
  int n = np + lrow;
  float bv = bias_t[h_orig(n)];
  #pragma unroll
  for (int j = 0; j < 4; ++j) {
    float v0 = fmaxf(a[j] + bv, 0.f);
    float p0 = __shfl_xor(v0, 1);
    if (ev) {
      int m = lk8 * 4 + j;
      unsigned int w = (unsigned int)__builtin_bit_cast(unsigned short, (f16)v0)
                     | ((unsigned int)__builtin_bit_cast(unsigned short, (f16)p0) << 16);
      int off = m * 1024 + n * 2;
      *(unsigned int*)((char*)dst + (off ^ ((m & 7) << 4))) = w;
    }
  }
}

__global__ __launch_bounds__(512, 4) void iaf_main(
    const float* __restrict__ mean, const float* __restrict__ logv,
    const float* __restrict__ eps,
    const float* __restrict__ b1, const float* __restrict__ b2,
    const float* __restrict__ b3,
    const f16* __restrict__ ws, float* __restrict__ out)
{
  __shared__ float xbuf[ROWS][XSTR];               // 16.6 KB fp32 master x
  __shared__ __align__(16) f16 buf0[ROWS * 512];   // 16 KB (A1 uses 8 KB)
  __shared__ __align__(16) f16 buf1[ROWS * 512];   // 16 KB -> 49.4 KB total

  const int tid = threadIdx.x;
  const int wid = tid >> 6;      // 0..7
  const int lane = tid & 63;
  const int lrow = lane & 15;    // MFMA row (A) / col (B,C)
  const int lk8 = lane >> 4;     // MFMA k-chunk / row-group
  const int row0 = blockIdx.x * ROWS;

  // wave w owns 4 tiles as two mirror pairs; per-wave cp totals constant:
  // W1: 5+... (pair sums 5 W1 / 9 W2 / 9 W3 each, rounded-even zeros-padded).
  const int tS1 = 2 * wid,     tB1 = 31 - 2 * wid;
  const int tS2 = 2 * wid + 1, tB2 = 30 - 2 * wid;
  const int npS1 = tS1 * 16, npB1 = tB1 * 16;
  const int npS2 = tS2 * 16, npB2 = tB2 * 16;
  const int nc1S1 = tS1 / 8 + 1, nc1B1 = tB1 / 8 + 1;
  const int nc1S2 = tS2 / 8 + 1, nc1B2 = tB2 / 8 + 1;
  const int nc23S1 = tS1 / 4 + 1, nc23B1 = tB1 / 4 + 1;
  const int nc23S2 = tS2 / 4 + 1, nc23B2 = tB2 / 4 + 1;

  // x0 = mean + exp(0.5*log_var)*eps   (512 thr x 8 floats = 16x256)
  {
    int m = tid >> 5;
    int c0 = (tid & 31) * 8;
    const int g = (row0 + m) * ND + c0;
    #pragma unroll
    for (int i = 0; i < 8; i += 4) {
      f32x4 mu = *(const f32x4*)(mean + g + i);
      f32x4 lv = *(const f32x4*)(logv + g + i);
      f32x4 ep = *(const f32x4*)(eps + g + i);
      f32x4 x;
      #pragma unroll
      for (int q = 0; q < 4; ++q) x[q] = mu[q] + __expf(0.5f * lv[q]) * ep[q];
      *(f32x4*)(&xbuf[m][c0 + i]) = x;
    }
  }
  __syncthreads();

  for (int t = NT - 1; t >= 0; --t) {
    // A1[m][k] = fp16(x[m][255-k]) (reversal folded), stride 512B, swizzled
    {
      int m = tid >> 5;
      int k0 = (tid & 31) * 8;
      f32x4 lo = *(const f32x4*)(&xbuf[m][248 - k0]);
      f32x4 hi = *(const f32x4*)(&xbuf[m][252 - k0]);
      f16x8 pk;
      pk[0] = (f16)hi[3]; pk[1] = (f16)hi[2]; pk[2] = (f16)hi[1]; pk[3] = (f16)hi[0];
      pk[4] = (f16)lo[3]; pk[5] = (f16)lo[2]; pk[6] = (f16)lo[1]; pk[7] = (f16)lo[0];
      int off = m * 512 + k0 * 2;
      *(f16x8*)((char*)buf0 + (off ^ ((m & 7) << 4))) = pk;
    }
    __syncthreads();

    f32x4 aS1, aB1, aS2, aB2;

    // h1 = relu(x_rev @ W1m + b1)
    {
      const f16* w1b = ws + W1F_OFF + t * (NH * ND);
      gemm_hyb16<512>(buf0, w1b + tS1 * 4096 + lane * 8,
                      w1b + tB1 * 4096 + lane * 8, nc1S1, nc1B1, lrow, lk8, aS1, aB1);
      gemm_hyb16<512>(buf0, w1b + tS2 * 4096 + lane * 8,
                      w1b + tB2 * 4096 + lane * 8, nc1S2, nc1B2, lrow, lk8, aS2, aB2);
      const float* bt = b1 + t * NH;
      epi16(aS1, bt, buf1, npS1, lrow, lk8);
      epi16(aB1, bt, buf1, npB1, lrow, lk8);
      epi16(aS2, bt, buf1, npS2, lrow, lk8);
      epi16(aB2, bt, buf1, npB2, lrow, lk8);
    }
    __syncthreads();

    // h2 = relu(h1 @ W2m + b2)
    {
      const f16* w2b = ws + W2F_OFF + t * (NH * NH);
      gemm_hyb16<1024>(buf1, w2b + tS1 * 8192 + lane * 8,
                       w2b + tB1 * 8192 + lane * 8, nc23S1, nc23B1, lrow, lk8, aS1, aB1);
      gemm_hyb16<1024>(buf1, w2b + tS2 * 8192 + lane * 8,
                       w2b + tB2 * 8192 + lane * 8, nc23S2, nc23B2, lrow, lk8, aS2, aB2);
      const float* bt = b2 + t * NH;
      epi16(aS1, bt, buf0, npS1, lrow, lk8);
      epi16(aB1, bt, buf0, npB1, lrow, lk8);
      epi16(aS2, bt, buf0, npS2, lrow, lk8);
      epi16(aB2, bt, buf0, npB2, lrow, lk8);
    }
    __syncthreads();

    // out = h2 @ W3m + b3 ; shift = out[:,2d], log_var = out[:,2d+1]
    {
      const f16* w3b = ws + W3F_OFF + t * (NH * NH);
      gemm_hyb16<1024>(buf0, w3b + tS1 * 8192 + lane * 8,
                       w3b + tB1 * 8192 + lane * 8, nc23S1, nc23B1, lrow, lk8, aS1, aB1);
      gemm_hyb16<1024>(buf0, w3b + tS2 * 8192 + lane * 8,
                       w3b + tB2 * 8192 + lane * 8, nc23S2, nc23B2, lrow, lk8, aS2, aB2);

      const bool ev = (lrow & 1) == 0;
      const float* b3t = b3 + t * (2 * ND);
      float xn1S[4], xn1B[4], xn2S[4], xn2B[4];
      #pragma unroll
      for (int pt = 0; pt < 4; ++pt) {
        f32x4 ac = (pt == 0) ? aS1 : (pt == 1) ? aB1 : (pt == 2) ? aS2 : aB2;
        float* xn = (pt == 0) ? xn1S : (pt == 1) ? xn1B : (pt == 2) ? xn2S : xn2B;
        int np = (pt == 0) ? npS1 : (pt == 1) ? npB1 : (pt == 2) ? npS2 : npB2;
        int n = np + lrow;
        float bv = b3t[n];
        #pragma unroll
        for (int j = 0; j < 4; ++j) {
          float o = ac[j] + bv;
          float po = __shfl_xor(o, 1);     // partner column (n^1) value
          if (ev) {                         // even col: o=shift, po=pre-tanh lv
            int d = n >> 1;
            float xc = xbuf[lk8 * 4 + j][255 - d];
            float e2 = __expf(2.f * po);
            float tl = 1.f - 2.f / (e2 + 1.f);          // tanh(po)
            xn[j] = (xc - o) * __expf(-tl);
          }
        }
      }
      __syncthreads();                      // all xbuf reads done
      if (ev) {
        int d1S = (npS1 + lrow) >> 1, d1B = (npB1 + lrow) >> 1;
        int d2S = (npS2 + lrow) >> 1, d2B = (npB2 + lrow) >> 1;
        #pragma unroll
        for (int j = 0; j < 4; ++j) {
          int m = lk8 * 4 + j;
          xbuf[m][d1S] = xn1S[j];
          xbuf[m][d1B] = xn1B[j];
          xbuf[m][d2S] = xn2S[j];
          xbuf[m][d2B] = xn2B[j];
        }
      }
      __syncthreads();
    }
  }

  // store final x (fp32)
  {
    int m = tid >> 5;
    int c0 = (tid & 31) * 8;
    float* op = out + (row0 + m) * ND + c0;
    #pragma unroll
    for (int i = 0; i < 8; i += 4)
      *(f32x4*)(op + i) = *(const f32x4*)(&xbuf[m][c0 + i]);
  }
}

extern "C" void kernel_launch(void* const* d_in, const int* in_sizes, int n_in,
                              void* d_out, int out_size, void* d_ws, size_t ws_size,
                              hipStream_t stream) {
  const float* mean = (const float*)d_in[0];
  const float* logv = (const float*)d_in[1];
  const float* eps  = (const float*)d_in[2];
  const float* W1   = (const float*)d_in[3];
  const float* b1   = (const float*)d_in[4];
  const float* W2   = (const float*)d_in[5];
  const float* b2   = (const float*)d_in[6];
  const float* W3   = (const float*)d_in[7];
  const float* b3   = (const float*)d_in[8];
  f16* ws = (f16*)d_ws;   // needs 5.25 MB

  prep_weights<<<(WS_ELEMS + 255) / 256, 256, 0, stream>>>(W1, W2, W3, ws);
  iaf_main<<<NB / ROWS, 512, 0, stream>>>(mean, logv, eps, b1, b2, b3, ws,
                                          (float*)d_out);
}

// Round 14
// 112.148 us; speedup vs baseline: 1.4304x; 1.4304x over previous
//
#include <hip/hip_runtime.h>

// IAF chain encoder, fully fused: one block = 32 batch rows, all 4 flow steps
// in-LDS. Degree-sorted hidden permutation makes all three MADE masks
// k-PREFIXES -> skip structurally-zero k-chunks. Round 14:
//  STATIC 2-case hybrid: mirror pairs (w,31-w) rounded to two compile-time
//  shapes -- wid<8: (ncS,ncB)=(2,8) W2/W3, (1,4) W1; wid>=8: (4,6),(2,3).
//  Both cases: identical MFMA count (40) and bytes (20KB/wave W2) -> balanced.
//  Fully unrolled static loops (r3's proven ring codegen; r12's runtime-trip
//  form measured 1.22x worse per work unit). Padded chunks are zeros (exact).

typedef _Float16 f16;
typedef __attribute__((ext_vector_type(8))) _Float16 f16x8;
typedef __attribute__((ext_vector_type(4))) float f32x4;

#define NB 8192
#define ND 256
#define NH 512
#define NT 4
#define XSTR 260   // xbuf row stride (floats)

// ws layout (fp16 els), fragment-native [T][tile=32][ks<KSMAX][lane=64][8]
// (fixed tile stride = KSMAX*512 els; chunks >= true nks(tile) are ZEROS)
#define W1F_OFF 0                        // KSMAX=8  : T*32*8*512  = T*NH*ND
#define W2F_OFF (NT*NH*ND)               // KSMAX=16 : T*32*16*512 = T*NH*NH
#define W3F_OFF (W2F_OFF + NT*NH*NH)     // KSMAX=16
#define WS_ELEMS (W3F_OFF + NT*NH*NH)    // 2,621,440 els = 5.24 MB

// Degree-sorted hidden permutation. deg_h[n] = 1 + n%255 over n in [0,512).
__device__ __forceinline__ int h_orig(int j) {
  if (j < 3) return j == 0 ? 0 : (j == 1 ? 255 : 510);
  if (j < 6) return j == 3 ? 1 : (j == 4 ? 256 : 511);
  int d = j >> 1;
  return (j & 1) ? (d + 254) : (d - 1);
}
__device__ __forceinline__ int h_deg(int j) {
  return (j < 3) ? 1 : (j < 6) ? 2 : (j >> 1);
}

// M1[k][j]: k <= deg(j)-1 ; M2[k][j]: deg(k) <= deg(j) ; M3[k][n]: deg(k) <= n>>1
__global__ void prep_weights(const float* __restrict__ W1,
                             const float* __restrict__ W2,
                             const float* __restrict__ W3,
                             f16* __restrict__ ws)
{
  int idx = blockIdx.x * blockDim.x + threadIdx.x;
  if (idx >= WS_ELEMS) return;
  float v;
  if (idx < W2F_OFF) {
    int t = idx >> 17, r = idx & ((1 << 17) - 1);     // 32*8*512 = 131072
    int e = r & 7, lane = (r >> 3) & 63, ks = (r >> 9) & 7, tile = r >> 12;
    int j = tile * 16 + (lane & 15);                  // sorted hidden col
    int k = ks * 32 + (lane >> 4) * 8 + e;            // raw input row
    v = (k <= h_deg(j) - 1) ? W1[t * (ND * NH) + k * NH + h_orig(j)] : 0.f;
  } else if (idx < W3F_OFF) {
    int q = idx - W2F_OFF;
    int t = q >> 18, r = q & ((1 << 18) - 1);         // 32*16*512 = 262144
    int e = r & 7, lane = (r >> 3) & 63, ks = (r >> 9) & 15, tile = r >> 13;
    int j = tile * 16 + (lane & 15);                  // sorted hidden col
    int k = ks * 32 + (lane >> 4) * 8 + e;            // sorted hidden row
    v = (h_deg(k) <= h_deg(j)) ? W2[t * (NH * NH) + h_orig(k) * NH + h_orig(j)] : 0.f;
  } else {
    int q = idx - W3F_OFF;
    int t = q >> 18, r = q & ((1 << 18) - 1);
    int e = r & 7, lane = (r >> 3) & 63, ks = (r >> 9) & 15, tile = r >> 13;
    int n = tile * 16 + (lane & 15);                  // raw output col
    int k = ks * 32 + (lane >> 4) * 8 + e;            // sorted hidden row
    v = (h_deg(k) <= (n >> 1)) ? W3[t * (NH * 2 * ND) + h_orig(k) * (2 * ND) + n] : 0.f;
  }
  ws[idx] = (f16)v;
}

#define MFMA16 __builtin_amdgcn_mfma_f32_16x16x32_f16

// Fully-static mirror-pair hybrid gemm. Compile-time (NCS,NCB):
// shared prefix [0,NCS) feeds tiles S+B from one A-read set; solo tail
// [NCS,NCB) feeds B only. Ring dbuf b[2][2], all indices static after unroll
// (r3's proven scratch-free shape).
template<int NCS, int NCB, int SSTRB>
__device__ __forceinline__ void gemm_stat(const f16* srcA,
                                          const f16* __restrict__ wtS,
                                          const f16* __restrict__ wtB,
                                          int lrow, int lk8,
                                          f32x4 &aS0, f32x4 &aS1,
                                          f32x4 &aB0, f32x4 &aB1)
{
  const f32x4 z = {0.f, 0.f, 0.f, 0.f};
  aS0 = z; aS1 = z; aB0 = z; aB1 = z;
  const int r1 = 16 + lrow;
  const int swz0 = (lrow & 7) << 4;
  const int swz1 = (r1 & 7) << 4;

  f16x8 bS[2][2], bB[2][2];   // [parity][ksub], static indices after unroll
  bS[0][0] = *(const f16x8*)(wtS);
  bS[0][1] = *(const f16x8*)(wtS + 512);
  bB[0][0] = *(const f16x8*)(wtB);
  bB[0][1] = *(const f16x8*)(wtB + 512);

  #pragma unroll
  for (int c = 0; c < NCS; ++c) {
    const int cur = c & 1, nxt = cur ^ 1;
    if (c + 1 < NCS) {
      bS[nxt][0] = *(const f16x8*)(wtS + (c + 1) * 1024);
      bS[nxt][1] = *(const f16x8*)(wtS + (c + 1) * 1024 + 512);
      bB[nxt][0] = *(const f16x8*)(wtB + (c + 1) * 1024);
      bB[nxt][1] = *(const f16x8*)(wtB + (c + 1) * 1024 + 512);
    } else if (NCS < NCB) {
      bB[nxt][0] = *(const f16x8*)(wtB + (c + 1) * 1024);
      bB[nxt][1] = *(const f16x8*)(wtB + (c + 1) * 1024 + 512);
    }
    #pragma unroll
    for (int u = 0; u < 2; ++u) {
      int kb = 128 * c + u * 64 + lk8 * 16;
      f16x8 a0 = *(const f16x8*)((const char*)srcA + ((lrow * SSTRB + kb) ^ swz0));
      f16x8 a1 = *(const f16x8*)((const char*)srcA + ((r1 * SSTRB + kb) ^ swz1));
      aS0 = MFMA16(a0, bS[cur][u], aS0, 0, 0, 0);
      aS1 = MFMA16(a1, bS[cur][u], aS1, 0, 0, 0);
      aB0 = MFMA16(a0, bB[cur][u], aB0, 0, 0, 0);
      aB1 = MFMA16(a1, bB[cur][u], aB1, 0, 0, 0);
    }
  }
  #pragma unroll
  for (int c = NCS; c < NCB; ++c) {
    const int cur = c & 1, nxt = cur ^ 1;
    if (c + 1 < NCB) {
      bB[nxt][0] = *(const f16x8*)(wtB + (c + 1) * 1024);
      bB[nxt][1] = *(const f16x8*)(wtB + (c + 1) * 1024 + 512);
    }
    #pragma unroll
    for (int u = 0; u < 2; ++u) {
      int kb = 128 * c + u * 64 + lk8 * 16;
      f16x8 a0 = *(const f16x8*)((const char*)srcA + ((lrow * SSTRB + kb) ^ swz0));
      f16x8 a1 = *(const f16x8*)((const char*)srcA + ((r1 * SSTRB + kb) ^ swz1));
      aB0 = MFMA16(a0, bB[cur][u], aB0, 0, 0, 0);
      aB1 = MFMA16(a1, bB[cur][u], aB1, 0, 0, 0);
    }
  }
}

// relu(acc + bias) -> fp16 LDS tile [32][512] (sorted cols), swizzled,
// row stride 1024B. Pair-stores via shfl_xor -> all-lane ds_write_b32.
__device__ __forceinline__ void epi_relu_tile(f32x4 a0, f32x4 a1,
                                              const float* __restrict__ bias_t,
                                              f16* dst, int np, int lrow, int lk8)
{
  const bool ev = (lrow & 1) == 0;
  int n = np + lrow;
  float bv = bias_t[h_orig(n)];
  #pragma unroll
  for (int j = 0; j < 4; ++j) {
    float v0 = fmaxf(a0[j] + bv, 0.f);
    float v1 = fmaxf(a1[j] + bv, 0.f);
    float p0 = __shfl_xor(v0, 1);
    float p1 = __shfl_xor(v1, 1);
    float lo = ev ? v0 : p1;
    float hi = ev ? p0 : v1;
    int m = (ev ? 0 : 16) + lk8 * 4 + j;
    int nw = n & ~1;
    unsigned int w = (unsigned int)__builtin_bit_cast(unsigned short, (f16)lo)
                   | ((unsigned int)__builtin_bit_cast(unsigned short, (f16)hi) << 16);
    int off = m * 1024 + nw * 2;
    *(unsigned int*)((char*)dst + (off ^ ((m & 7) << 4))) = w;
  }
}

__global__ __launch_bounds__(1024, 4) void iaf_main(
    const float* __restrict__ mean, const float* __restrict__ logv,
    const float* __restrict__ eps,
    const float* __restrict__ b1, const float* __restrict__ b2,
    const float* __restrict__ b3,
    const f16* __restrict__ ws, float* __restrict__ out)
{
  __shared__ float xbuf[32][XSTR];                // 33.3 KB fp32 master x
  __shared__ __align__(16) f16 buf0[32 * 512];    // 32 KB (A1 uses 16 KB)
  __shared__ __align__(16) f16 buf1[32 * 512];    // 32 KB

  const int tid = threadIdx.x;
  const int wid = tid >> 6;
  const int lane = tid & 63;
  const int lrow = lane & 15;    // MFMA row (A) / col (B,C)
  const int lk8 = lane >> 4;     // MFMA k-chunk / row-group
  const int row0 = blockIdx.x * 32;
  const bool lo = (wid < 8);

  // mirror pairing: wave w owns tiles {w, 31-w}. Static 2-case shapes:
  //  wid<8:  W1 (1,4), W2/W3 (2,8)   [covers true extents; pads are zeros]
  //  wid>=8: W1 (2,3), W2/W3 (4,6)
  const int tS = wid, tB = 31 - wid;
  const int npS = tS * 16, npB = tB * 16;

  // x0 = mean + exp(0.5*log_var)*eps
  {
    int m = tid >> 5;
    int c0 = (tid & 31) * 8;
    const int g = (row0 + m) * ND + c0;
    #pragma unroll
    for (int i = 0; i < 8; i += 4) {
      f32x4 mu = *(const f32x4*)(mean + g + i);
      f32x4 lv = *(const f32x4*)(logv + g + i);
      f32x4 ep = *(const f32x4*)(eps + g + i);
      f32x4 x;
      #pragma unroll
      for (int q = 0; q < 4; ++q) x[q] = mu[q] + __expf(0.5f * lv[q]) * ep[q];
      *(f32x4*)(&xbuf[m][c0 + i]) = x;
    }
  }
  __syncthreads();

  for (int t = NT - 1; t >= 0; --t) {
    // A1[m][k] = fp16(x[m][255-k]) (reversal folded in), stride 512B, swizzled
    {
      int m = tid >> 5;
      int k0 = (tid & 31) * 8;
      f32x4 lof = *(const f32x4*)(&xbuf[m][248 - k0]);
      f32x4 hif = *(const f32x4*)(&xbuf[m][252 - k0]);
      f16x8 pk;
      pk[0] = (f16)hif[3]; pk[1] = (f16)hif[2]; pk[2] = (f16)hif[1]; pk[3] = (f16)hif[0];
      pk[4] = (f16)lof[3]; pk[5] = (f16)lof[2]; pk[6] = (f16)lof[1]; pk[7] = (f16)lof[0];
      int off = m * 512 + k0 * 2;
      *(f16x8*)((char*)buf0 + (off ^ ((m & 7) << 4))) = pk;
    }
    __syncthreads();

    f32x4 aS0, aS1, aB0, aB1;

    // h1 = relu(x_rev @ W1m + b1)   (sorted cols)
    {
      const f16* w1b = ws + W1F_OFF + t * (NH * ND);
      const f16* pS = w1b + tS * 4096 + lane * 8;
      const f16* pB = w1b + tB * 4096 + lane * 8;
      if (lo) gemm_stat<1, 4, 512>(buf0, pS, pB, lrow, lk8, aS0, aS1, aB0, aB1);
      else    gemm_stat<2, 3, 512>(buf0, pS, pB, lrow, lk8, aS0, aS1, aB0, aB1);
      epi_relu_tile(aS0, aS1, b1 + t * NH, buf1, npS, lrow, lk8);
      epi_relu_tile(aB0, aB1, b1 + t * NH, buf1, npB, lrow, lk8);
    }
    __syncthreads();

    // h2 = relu(h1 @ W2m + b2)   (sorted rows+cols)
    {
      const f16* w2b = ws + W2F_OFF + t * (NH * NH);
      const f16* pS = w2b + tS * 8192 + lane * 8;
      const f16* pB = w2b + tB * 8192 + lane * 8;
      if (lo) gemm_stat<2, 8, 1024>(buf1, pS, pB, lrow, lk8, aS0, aS1, aB0, aB1);
      else    gemm_stat<4, 6, 1024>(buf1, pS, pB, lrow, lk8, aS0, aS1, aB0, aB1);
      epi_relu_tile(aS0, aS1, b2 + t * NH, buf0, npS, lrow, lk8);
      epi_relu_tile(aB0, aB1, b2 + t * NH, buf0, npB, lrow, lk8);
    }
    __syncthreads();

    // out = h2 @ W3m + b3 ;  shift = out[:,2d], log_var = out[:,2d+1]
    {
      const f16* w3b = ws + W3F_OFF + t * (NH * NH);
      const f16* pS = w3b + tS * 8192 + lane * 8;
      const f16* pB = w3b + tB * 8192 + lane * 8;
      if (lo) gemm_stat<2, 8, 1024>(buf0, pS, pB, lrow, lk8, aS0, aS1, aB0, aB1);
      else    gemm_stat<4, 6, 1024>(buf0, pS, pB, lrow, lk8, aS0, aS1, aB0, aB1);

      const bool ev = (lrow & 1) == 0;
      const float* b3t = b3 + t * (2 * ND);
      float xnS[2][4], xnB[2][4];
      #pragma unroll
      for (int pt = 0; pt < 2; ++pt) {
        f32x4 o_0 = pt ? aB0 : aS0;
        f32x4 o_1 = pt ? aB1 : aS1;
        float (*xn)[4] = pt ? xnB : xnS;
        int n = (pt ? npB : npS) + lrow;
        float bv = b3t[n];
        #pragma unroll
        for (int j = 0; j < 4; ++j) {
          float o0 = o_0[j] + bv;
          float o1 = o_1[j] + bv;
          float po0 = __shfl_xor(o0, 1);   // partner column (n^1) value
          float po1 = __shfl_xor(o1, 1);
          if (ev) {                         // even col: o=shift, po=pre-tanh lv
            int d = n >> 1;
            float xc0 = xbuf[lk8 * 4 + j][255 - d];
            float e0 = __expf(2.f * po0);
            float t0 = 1.f - 2.f / (e0 + 1.f);          // tanh(po0)
            xn[0][j] = (xc0 - o0) * __expf(-t0);
            float xc1 = xbuf[16 + lk8 * 4 + j][255 - d];
            float e1 = __expf(2.f * po1);
            float t1 = 1.f - 2.f / (e1 + 1.f);
            xn[1][j] = (xc1 - o1) * __expf(-t1);
          }
        }
      }
      __syncthreads();                      // all xbuf reads done
      if (ev) {
        int dS = (npS + lrow) >> 1;
        int dB = (npB + lrow) >> 1;
        #pragma unroll
        for (int j = 0; j < 4; ++j) {
          xbuf[lk8 * 4 + j][dS]      = xnS[0][j];
          xbuf[16 + lk8 * 4 + j][dS] = xnS[1][j];
          xbuf[lk8 * 4 + j][dB]      = xnB[0][j];
          xbuf[16 + lk8 * 4 + j][dB] = xnB[1][j];
        }
      }
      __syncthreads();
    }
  }

  // store final x (fp32)
  {
    int m = tid >> 5;
    int c0 = (tid & 31) * 8;
    float* op = out + (row0 + m) * ND + c0;
    #pragma unroll
    for (int i = 0; i < 8; i += 4)
      *(f32x4*)(op + i) = *(const f32x4*)(&xbuf[m][c0 + i]);
  }
}

extern "C" void kernel_launch(void* const* d_in, const int* in_sizes, int n_in,
                              void* d_out, int out_size, void* d_ws, size_t ws_size,
                              hipStream_t stream) {
  const float* mean = (const float*)d_in[0];
  const float* logv = (const float*)d_in[1];
  const float* eps  = (const float*)d_in[2];
  const float* W1   = (const float*)d_in[3];
  const float* b1   = (const float*)d_in[4];
  const float* W2   = (const float*)d_in[5];
  const float* b2   = (const float*)d_in[6];
  const float* W3   = (const float*)d_in[7];
  const float* b3   = (const float*)d_in[8];
  f16* ws = (f16*)d_ws;   // needs 5.25 MB

  prep_weights<<<(WS_ELEMS + 255) / 256, 256, 0, stream>>>(W1, W2, W3, ws);
  iaf_main<<<NB / 32, 1024, 0, stream>>>(mean, logv, eps, b1, b2, b3, ws,
                                         (float*)d_out);
}

// Round 15
// 90.233 us; speedup vs baseline: 1.7778x; 1.2429x over previous
//
#include <hip/hip_runtime.h>

// IAF chain encoder, fully fused: one block = 32 batch rows, all 4 flow steps
// in-LDS. Degree-sorted hidden permutation makes all three MADE masks
// k-PREFIXES -> skip structurally-zero k-chunks. Round 15:
//  8 FAT WAVES (512 thr, 2 waves/SIMD, VGPR cap 256): each wave owns 4 tiles
//  {w,15-w,16+w,31-w} (nc ascending, per-wave totals constant 10/18/18 cp).
//  One ping-pong loop (2-chunk unroll, X/Y named bufs -> no copy movs) with
//  wave-uniform stream-retirement -> each A-read feeds up to 4 B-streams:
//  LDS A-reads/CU/step 1056 -> 600 (the dominant measured pipe, r3 evidence).

typedef _Float16 f16;
typedef __attribute__((ext_vector_type(8))) _Float16 f16x8;
typedef __attribute__((ext_vector_type(4))) float f32x4;

#define NB 8192
#define ND 256
#define NH 512
#define NT 4
#define XSTR 260   // xbuf row stride (floats)

// ws layout (fp16 els), fragment-native [T][tile=32][ks<KSMAX][lane=64][8]
// (fixed tile stride = KSMAX*512 els; chunks >= true nks(tile) are ZEROS)
#define W1F_OFF 0                        // KSMAX=8  : T*32*8*512  = T*NH*ND
#define W2F_OFF (NT*NH*ND)               // KSMAX=16 : T*32*16*512 = T*NH*NH
#define W3F_OFF (W2F_OFF + NT*NH*NH)     // KSMAX=16
#define WS_ELEMS (W3F_OFF + NT*NH*NH)    // 2,621,440 els = 5.24 MB

// Degree-sorted hidden permutation. deg_h[n] = 1 + n%255 over n in [0,512).
__device__ __forceinline__ int h_orig(int j) {
  if (j < 3) return j == 0 ? 0 : (j == 1 ? 255 : 510);
  if (j < 6) return j == 3 ? 1 : (j == 4 ? 256 : 511);
  int d = j >> 1;
  return (j & 1) ? (d + 254) : (d - 1);
}
__device__ __forceinline__ int h_deg(int j) {
  return (j < 3) ? 1 : (j < 6) ? 2 : (j >> 1);
}

// M1[k][j]: k <= deg(j)-1 ; M2[k][j]: deg(k) <= deg(j) ; M3[k][n]: deg(k) <= n>>1
__global__ void prep_weights(const float* __restrict__ W1,
                             const float* __restrict__ W2,
                             const float* __restrict__ W3,
                             f16* __restrict__ ws)
{
  int idx = blockIdx.x * blockDim.x + threadIdx.x;
  if (idx >= WS_ELEMS) return;
  float v;
  if (idx < W2F_OFF) {
    int t = idx >> 17, r = idx & ((1 << 17) - 1);     // 32*8*512 = 131072
    int e = r & 7, lane = (r >> 3) & 63, ks = (r >> 9) & 7, tile = r >> 12;
    int j = tile * 16 + (lane & 15);                  // sorted hidden col
    int k = ks * 32 + (lane >> 4) * 8 + e;            // raw input row
    v = (k <= h_deg(j) - 1) ? W1[t * (ND * NH) + k * NH + h_orig(j)] : 0.f;
  } else if (idx < W3F_OFF) {
    int q = idx - W2F_OFF;
    int t = q >> 18, r = q & ((1 << 18) - 1);         // 32*16*512 = 262144
    int e = r & 7, lane = (r >> 3) & 63, ks = (r >> 9) & 15, tile = r >> 13;
    int j = tile * 16 + (lane & 15);                  // sorted hidden col
    int k = ks * 32 + (lane >> 4) * 8 + e;            // sorted hidden row
    v = (h_deg(k) <= h_deg(j)) ? W2[t * (NH * NH) + h_orig(k) * NH + h_orig(j)] : 0.f;
  } else {
    int q = idx - W3F_OFF;
    int t = q >> 18, r = q & ((1 << 18) - 1);
    int e = r & 7, lane = (r >> 3) & 63, ks = (r >> 9) & 15, tile = r >> 13;
    int n = tile * 16 + (lane & 15);                  // raw output col
    int k = ks * 32 + (lane >> 4) * 8 + e;            // sorted hidden row
    v = (h_deg(k) <= (n >> 1)) ? W3[t * (NH * 2 * ND) + h_orig(k) * (2 * ND) + n] : 0.f;
  }
  ws[idx] = (f16)v;
}

#define MFMA16 __builtin_amdgcn_mfma_f32_16x16x32_f16

// Quad-stream gemm: 4 tiles with ascending wave-uniform chunk counts
// n0<=n1<=n2<=n3; one loop over c in [0,n3); stream s active while c<ns.
// Ping-pong X/Y named buffers (2-chunk unroll) -> no inter-buffer movs.
template<int SSTRB>
__device__ __forceinline__ void gemm_quad(const f16* srcA,
    const f16* __restrict__ w0p, const f16* __restrict__ w1p,
    const f16* __restrict__ w2p, const f16* __restrict__ w3p,
    int n0, int n1, int n2, int n3, int lrow, int lk8,
    f32x4 &a0L, f32x4 &a0H, f32x4 &a1L, f32x4 &a1H,
    f32x4 &a2L, f32x4 &a2H, f32x4 &a3L, f32x4 &a3H)
{
  const f32x4 z = {0.f, 0.f, 0.f, 0.f};
  a0L = z; a0H = z; a1L = z; a1H = z; a2L = z; a2H = z; a3L = z; a3H = z;
  const int r1 = 16 + lrow;
  const int swz0 = (lrow & 7) << 4;
  const int swz1 = (r1 & 7) << 4;

  f16x8 X00, X01, X10, X11, X20, X21, X30, X31;
  f16x8 Y00, Y01, Y10, Y11, Y20, Y21, Y30, Y31;

#define LDC(B0, B1, P, ci) do {                          \
    B0 = *(const f16x8*)((P) + (ci) * 1024);             \
    B1 = *(const f16x8*)((P) + (ci) * 1024 + 512);       \
  } while (0)

  LDC(X00, X01, w0p, 0); LDC(X10, X11, w1p, 0);
  LDC(X20, X21, w2p, 0); LDC(X30, X31, w3p, 0);

#define QBODY(cc, I00,I01,I10,I11,I20,I21,I30,I31, O00,O01,O10,O11,O20,O21,O30,O31) \
  do {                                                                         \
    if ((cc) + 1 < n0) LDC(O00, O01, w0p, (cc) + 1);                           \
    if ((cc) + 1 < n1) LDC(O10, O11, w1p, (cc) + 1);                           \
    if ((cc) + 1 < n2) LDC(O20, O21, w2p, (cc) + 1);                           \
    if ((cc) + 1 < n3) LDC(O30, O31, w3p, (cc) + 1);                           \
    int kb = 128 * (cc) + lk8 * 16;                                            \
    f16x8 aL0 = *(const f16x8*)((const char*)srcA + ((lrow * SSTRB + kb) ^ swz0)); \
    f16x8 aH0 = *(const f16x8*)((const char*)srcA + ((r1 * SSTRB + kb) ^ swz1));   \
    f16x8 aL1 = *(const f16x8*)((const char*)srcA + ((lrow * SSTRB + kb + 64) ^ swz0)); \
    f16x8 aH1 = *(const f16x8*)((const char*)srcA + ((r1 * SSTRB + kb + 64) ^ swz1));   \
    if ((cc) < n0) {                                                           \
      a0L = MFMA16(aL0, I00, a0L, 0, 0, 0); a0H = MFMA16(aH0, I00, a0H, 0, 0, 0); \
      a0L = MFMA16(aL1, I01, a0L, 0, 0, 0); a0H = MFMA16(aH1, I01, a0H, 0, 0, 0); \
    }                                                                          \
    if ((cc) < n1) {                                                           \
      a1L = MFMA16(aL0, I10, a1L, 0, 0, 0); a1H = MFMA16(aH0, I10, a1H, 0, 0, 0); \
      a1L = MFMA16(aL1, I11, a1L, 0, 0, 0); a1H = MFMA16(aH1, I11, a1H, 0, 0, 0); \
    }                                                                          \
    if ((cc) < n2) {                                                           \
      a2L = MFMA16(aL0, I20, a2L, 0, 0, 0); a2H = MFMA16(aH0, I20, a2H, 0, 0, 0); \
      a2L = MFMA16(aL1, I21, a2L, 0, 0, 0); a2H = MFMA16(aH1, I21, a2H, 0, 0, 0); \
    }                                                                          \
    a3L = MFMA16(aL0, I30, a3L, 0, 0, 0); a3H = MFMA16(aH0, I30, a3H, 0, 0, 0); \
    a3L = MFMA16(aL1, I31, a3L, 0, 0, 0); a3H = MFMA16(aH1, I31, a3H, 0, 0, 0); \
  } while (0)

  int c = 0;
  for (;;) {
    QBODY(c, X00,X01,X10,X11,X20,X21,X30,X31, Y00,Y01,Y10,Y11,Y20,Y21,Y30,Y31);
    if (++c >= n3) break;
    QBODY(c, Y00,Y01,Y10,Y11,Y20,Y21,Y30,Y31, X00,X01,X10,X11,X20,X21,X30,X31);
    if (++c >= n3) break;
  }
#undef QBODY
#undef LDC
}

// relu(acc + bias) -> fp16 LDS tile [32][512] (sorted cols), swizzled,
// row stride 1024B. Pair-stores via shfl_xor -> all-lane ds_write_b32.
__device__ __forceinline__ void epi_relu_tile(f32x4 a0, f32x4 a1,
                                              const float* __restrict__ bias_t,
                                              f16* dst, int np, int lrow, int lk8)
{
  const bool ev = (lrow & 1) == 0;
  int n = np + lrow;
  float bv = bias_t[h_orig(n)];
  #pragma unroll
  for (int j = 0; j < 4; ++j) {
    float v0 = fmaxf(a0[j] + bv, 0.f);
    float v1 = fmaxf(a1[j] + bv, 0.f);
    float p0 = __shfl_xor(v0, 1);
    float p1 = __shfl_xor(v1, 1);
    float lo = ev ? v0 : p1;
    float hi = ev ? p0 : v1;
    int m = (ev ? 0 : 16) + lk8 * 4 + j;
    int nw = n & ~1;
    unsigned int w = (unsigned int)__builtin_bit_cast(unsigned short, (f16)lo)
                   | ((unsigned int)__builtin_bit_cast(unsigned short, (f16)hi) << 16);
    int off = m * 1024 + nw * 2;
    *(unsigned int*)((char*)dst + (off ^ ((m & 7) << 4))) = w;
  }
}

__global__ __launch_bounds__(512, 2) void iaf_main(
    const float* __restrict__ mean, const float* __restrict__ logv,
    const float* __restrict__ eps,
    const float* __restrict__ b1, const float* __restrict__ b2,
    const float* __restrict__ b3,
    const f16* __restrict__ ws, float* __restrict__ out)
{
  __shared__ float xbuf[32][XSTR];                // 33.3 KB fp32 master x
  __shared__ __align__(16) f16 buf0[32 * 512];    // 32 KB (A1 uses 16 KB)
  __shared__ __align__(16) f16 buf1[32 * 512];    // 32 KB

  const int tid = threadIdx.x;
  const int wid = tid >> 6;      // 0..7
  const int lane = tid & 63;
  const int lrow = lane & 15;    // MFMA row (A) / col (B,C)
  const int lk8 = lane >> 4;     // MFMA k-chunk / row-group
  const int row0 = blockIdx.x * 32;

  // wave w owns 4 tiles, ascending nc; per-wave cp totals constant.
  const int t0 = wid, t1 = 15 - wid, t2 = 16 + wid, t3 = 31 - wid;
  const int np0 = t0 * 16, np1 = t1 * 16, np2 = t2 * 16, np3 = t3 * 16;
  const int n1_0 = t0 / 8 + 1, n1_1 = t1 / 8 + 1, n1_2 = t2 / 8 + 1, n1_3 = t3 / 8 + 1;
  const int n2_0 = t0 / 4 + 1, n2_1 = t1 / 4 + 1, n2_2 = t2 / 4 + 1, n2_3 = t3 / 4 + 1;

  // x0 = mean + exp(0.5*log_var)*eps   (512 thr x 16 floats = 32x256)
  {
    int m = tid >> 4;
    int c0 = (tid & 15) * 16;
    const int g = (row0 + m) * ND + c0;
    #pragma unroll
    for (int i = 0; i < 16; i += 4) {
      f32x4 mu = *(const f32x4*)(mean + g + i);
      f32x4 lv = *(const f32x4*)(logv + g + i);
      f32x4 ep = *(const f32x4*)(eps + g + i);
      f32x4 x;
      #pragma unroll
      for (int q = 0; q < 4; ++q) x[q] = mu[q] + __expf(0.5f * lv[q]) * ep[q];
      *(f32x4*)(&xbuf[m][c0 + i]) = x;
    }
  }
  __syncthreads();

  for (int t = NT - 1; t >= 0; --t) {
    // A1[m][k] = fp16(x[m][255-k]) (reversal folded), stride 512B, swizzled
    {
      int m = tid >> 4;
      #pragma unroll
      for (int half = 0; half < 2; ++half) {
        int k0 = (tid & 15) * 8 + half * 128;
        f32x4 lof = *(const f32x4*)(&xbuf[m][248 - k0]);
        f32x4 hif = *(const f32x4*)(&xbuf[m][252 - k0]);
        f16x8 pk;
        pk[0] = (f16)hif[3]; pk[1] = (f16)hif[2]; pk[2] = (f16)hif[1]; pk[3] = (f16)hif[0];
        pk[4] = (f16)lof[3]; pk[5] = (f16)lof[2]; pk[6] = (f16)lof[1]; pk[7] = (f16)lof[0];
        int off = m * 512 + k0 * 2;
        *(f16x8*)((char*)buf0 + (off ^ ((m & 7) << 4))) = pk;
      }
    }
    __syncthreads();

    f32x4 a0L, a0H, a1L, a1H, a2L, a2H, a3L, a3H;

    // h1 = relu(x_rev @ W1m + b1)   (sorted cols)
    {
      const f16* w1b = ws + W1F_OFF + t * (NH * ND);
      gemm_quad<512>(buf0,
                     w1b + t0 * 4096 + lane * 8, w1b + t1 * 4096 + lane * 8,
                     w1b + t2 * 4096 + lane * 8, w1b + t3 * 4096 + lane * 8,
                     n1_0, n1_1, n1_2, n1_3, lrow, lk8,
                     a0L, a0H, a1L, a1H, a2L, a2H, a3L, a3H);
      const float* bt = b1 + t * NH;
      epi_relu_tile(a0L, a0H, bt, buf1, np0, lrow, lk8);
      epi_relu_tile(a1L, a1H, bt, buf1, np1, lrow, lk8);
      epi_relu_tile(a2L, a2H, bt, buf1, np2, lrow, lk8);
      epi_relu_tile(a3L, a3H, bt, buf1, np3, lrow, lk8);
    }
    __syncthreads();

    // h2 = relu(h1 @ W2m + b2)   (sorted rows+cols)
    {
      const f16* w2b = ws + W2F_OFF + t * (NH * NH);
      gemm_quad<1024>(buf1,
                      w2b + t0 * 8192 + lane * 8, w2b + t1 * 8192 + lane * 8,
                      w2b + t2 * 8192 + lane * 8, w2b + t3 * 8192 + lane * 8,
                      n2_0, n2_1, n2_2, n2_3, lrow, lk8,
                      a0L, a0H, a1L, a1H, a2L, a2H, a3L, a3H);
      const float* bt = b2 + t * NH;
      epi_relu_tile(a0L, a0H, bt, buf0, np0, lrow, lk8);
      epi_relu_tile(a1L, a1H, bt, buf0, np1, lrow, lk8);
      epi_relu_tile(a2L, a2H, bt, buf0, np2, lrow, lk8);
      epi_relu_tile(a3L, a3H, bt, buf0, np3, lrow, lk8);
    }
    __syncthreads();

    // out = h2 @ W3m + b3 ;  shift = out[:,2d], log_var = out[:,2d+1]
    {
      const f16* w3b = ws + W3F_OFF + t * (NH * NH);
      gemm_quad<1024>(buf0,
                      w3b + t0 * 8192 + lane * 8, w3b + t1 * 8192 + lane * 8,
                      w3b + t2 * 8192 + lane * 8, w3b + t3 * 8192 + lane * 8,
                      n2_0, n2_1, n2_2, n2_3, lrow, lk8,
                      a0L, a0H, a1L, a1H, a2L, a2H, a3L, a3H);

      const bool ev = (lrow & 1) == 0;
      const float* b3t = b3 + t * (2 * ND);
      float xn0L[4], xn0H[4], xn1L[4], xn1H[4];
      float xn2L[4], xn2H[4], xn3L[4], xn3H[4];

#define STEP3T(AL, AH, NP, XL, XH) do {                                       \
    int n = (NP) + lrow;                                                      \
    float bv = b3t[n];                                                        \
    _Pragma("unroll")                                                         \
    for (int j = 0; j < 4; ++j) {                                             \
      float o0 = (AL)[j] + bv;                                                \
      float o1 = (AH)[j] + bv;                                                \
      float po0 = __shfl_xor(o0, 1);                                          \
      float po1 = __shfl_xor(o1, 1);                                          \
      if (ev) {                                                               \
        int d = n >> 1;                                                       \
        float xc0 = xbuf[lk8 * 4 + j][255 - d];                               \
        float e0 = __expf(2.f * po0);                                         \
        float t0v = 1.f - 2.f / (e0 + 1.f);                                   \
        (XL)[j] = (xc0 - o0) * __expf(-t0v);                                  \
        float xc1 = xbuf[16 + lk8 * 4 + j][255 - d];                          \
        float e1 = __expf(2.f * po1);                                         \
        float t1v = 1.f - 2.f / (e1 + 1.f);                                   \
        (XH)[j] = (xc1 - o1) * __expf(-t1v);                                  \
      }                                                                       \
    }                                                                         \
  } while (0)

      STEP3T(a0L, a0H, np0, xn0L, xn0H);
      STEP3T(a1L, a1H, np1, xn1L, xn1H);
      STEP3T(a2L, a2H, np2, xn2L, xn2H);
      STEP3T(a3L, a3H, np3, xn3L, xn3H);
#undef STEP3T

      __syncthreads();                      // all xbuf reads done
      if (ev) {
        int d0 = (np0 + lrow) >> 1, d1 = (np1 + lrow) >> 1;
        int d2 = (np2 + lrow) >> 1, d3 = (np3 + lrow) >> 1;
        #pragma unroll
        for (int j = 0; j < 4; ++j) {
          int mL = lk8 * 4 + j, mH = 16 + lk8 * 4 + j;
          xbuf[mL][d0] = xn0L[j]; xbuf[mH][d0] = xn0H[j];
          xbuf[mL][d1] = xn1L[j]; xbuf[mH][d1] = xn1H[j];
          xbuf[mL][d2] = xn2L[j]; xbuf[mH][d2] = xn2H[j];
          xbuf[mL][d3] = xn3L[j]; xbuf[mH][d3] = xn3H[j];
        }
      }
      __syncthreads();
    }
  }

  // store final x (fp32)
  {
    int m = tid >> 4;
    int c0 = (tid & 15) * 16;
    float* op = out + (row0 + m) * ND + c0;
    #pragma unroll
    for (int i = 0; i < 16; i += 4)
      *(f32x4*)(op + i) = *(const f32x4*)(&xbuf[m][c0 + i]);
  }
}

extern "C" void kernel_launch(void* const* d_in, const int* in_sizes, int n_in,
                              void* d_out, int out_size, void* d_ws, size_t ws_size,
                              hipStream_t stream) {
  const float* mean = (const float*)d_in[0];
  const float* logv = (const float*)d_in[1];
  const float* eps  = (const float*)d_in[2];
  const float* W1   = (const float*)d_in[3];
  const float* b1   = (const float*)d_in[4];
  const float* W2   = (const float*)d_in[5];
  const float* b2   = (const float*)d_in[6];
  const float* W3   = (const float*)d_in[7];
  const float* b3   = (const float*)d_in[8];
  f16* ws = (f16*)d_ws;   // needs 5.25 MB

  prep_weights<<<(WS_ELEMS + 255) / 256, 256, 0, stream>>>(W1, W2, W3, ws);
  iaf_main<<<NB / 32, 512, 0, stream>>>(mean, logv, eps, b1, b2, b3, ws,
                                        (float*)d_out);
}